// Round 13
// baseline (305.791 us; speedup 1.0000x reference)
//
#include <hip/hip_runtime.h>
#include <hip/hip_bf16.h>
#include <stdint.h>

// Problem constants (FC_Caps): B=32, I=1024, O=64, D_out=32, D_in=16
#define B_  32
#define I_  1024
#define O_  64
#define D_  32
#define N_  16
#define OD_ 2048   // O_*D_

// u_hat PERMUTED layout (since R12): per (b,i) row of 4 KB, element (o,d) at
// bf16 offset (d>>3)*512 + o*8 + (d&7). Route reads 4-KB dense wave segments.

// ---------- bf16 helpers (bit-exact RNE pack, shift unpack) ----------
__device__ __forceinline__ uint32_t f2bf1(float f) {
  uint32_t u = __float_as_uint(f);
  return (u + 0x7fffu + ((u >> 16) & 1u)) >> 16;
}
__device__ __forceinline__ uint32_t pack2(float a, float b) {
  return f2bf1(a) | (f2bf1(b) << 16);
}
__device__ __forceinline__ float bflo(uint32_t v) { return __uint_as_float(v << 16); }
__device__ __forceinline__ float bfhi(uint32_t v) { return __uint_as_float(v & 0xffff0000u); }
__device__ __forceinline__ void unpack8(uint4 r, float* u) {
  u[0] = bflo(r.x); u[1] = bfhi(r.x);
  u[2] = bflo(r.y); u[3] = bfhi(r.y);
  u[4] = bflo(r.z); u[5] = bfhi(r.z);
  u[6] = bflo(r.w); u[7] = bfhi(r.w);
}

// ---------- K1: einsum (R12 compute, bit-exact) — SPLIT into two od-half dispatches ----------
// R13: visibility play. Route (~80 us x2 = 54% of runtime) has sat just below
// the top-5 cutoff (einsum 83 us) all session; 4 route theories refuted blind.
// Halving einsum's dispatch duration (43-48 us) puts k_route at the top of the
// profile with full counters. Per-block work is bit-identical (q from param).
__global__ __launch_bounds__(256) void k_einsum(const float* __restrict__ x,
                                                const float* __restrict__ W,
                                                uint16_t* __restrict__ uhat,
                                                int qbase) {
  const int i = blockIdx.x >> 1;
  const int q = qbase | (blockIdx.x & 1);
  const int t = threadIdx.x;
  const int u = q * 256 + t;            // uint32 unit within the 1024-unit row
  const int o  = (u >> 2) & 63;
  const int dp = u & 3;
  const int od0 = o * 32 + q * 8 + dp * 2;   // this thread owns od0, od0+1
  __shared__ float xs[B_ * N_];
  for (int e = t; e < B_ * N_; e += 256) {
    int bb = e >> 4, n = e & 15;
    xs[e] = x[(size_t)bb * (I_ * N_) + (size_t)i * N_ + n];
  }
  float wA[16], wB[16];
  {
    const float4* Wp = (const float4*)(W + (size_t)i * (OD_ * N_) + (size_t)od0 * N_);
    #pragma unroll
    for (int qq = 0; qq < 4; ++qq) {
      float4 fa = Wp[qq];
      wA[qq * 4 + 0] = fa.x; wA[qq * 4 + 1] = fa.y;
      wA[qq * 4 + 2] = fa.z; wA[qq * 4 + 3] = fa.w;
      float4 fb = Wp[4 + qq];
      wB[qq * 4 + 0] = fb.x; wB[qq * 4 + 1] = fb.y;
      wB[qq * 4 + 2] = fb.z; wB[qq * 4 + 3] = fb.w;
    }
  }
  __syncthreads();
  uint32_t* u32 = (uint32_t*)uhat;
  #pragma unroll 2
  for (int bb = 0; bb < B_; ++bb) {
    float4 x0 = ((const float4*)(xs + bb * 16))[0];
    float4 x1 = ((const float4*)(xs + bb * 16))[1];
    float4 x2 = ((const float4*)(xs + bb * 16))[2];
    float4 x3 = ((const float4*)(xs + bb * 16))[3];
    float xv[16] = {x0.x, x0.y, x0.z, x0.w, x1.x, x1.y, x1.z, x1.w,
                    x2.x, x2.y, x2.z, x2.w, x3.x, x3.y, x3.z, x3.w};
    float a0 = 0.f, a1 = 0.f;
    #pragma unroll
    for (int n = 0; n < 16; ++n) {
      a0 = fmaf(wA[n], xv[n], a0);
      a1 = fmaf(wB[n], xv[n], a1);
    }
    u32[((size_t)bb * I_ + i) * 1024 + u] = pack2(a0, a1);
  }
}

// ---------- K2: iter-0 sum — element-wise over the stream, layout-agnostic ----------
// (frozen 25-us pattern)
__global__ __launch_bounds__(256) void k_sum0(const uint4* __restrict__ uhat,
                                              uint4* __restrict__ part) {
  const int b = blockIdx.x >> 5, chunk = blockIdx.x & 31;
  const int t = threadIdx.x;
  float acc[8] = {0.f, 0.f, 0.f, 0.f, 0.f, 0.f, 0.f, 0.f};
  const size_t ubase = (((size_t)b * I_ + (size_t)chunk * 32) * OD_ + (size_t)t * 8) >> 3;
  #pragma unroll 8
  for (int ii = 0; ii < 32; ++ii) {
    uint4 r = uhat[ubase + (size_t)ii * (OD_ / 8)];
    float u[8]; unpack8(r, u);
    #pragma unroll
    for (int j = 0; j < 8; ++j) acc[j] += u[j];
  }
  part[(((size_t)b * 32 + chunk) * OD_ + (size_t)t * 8) >> 3] =
      make_uint4(pack2(acc[0], acc[1]), pack2(acc[2], acc[3]),
                 pack2(acc[4], acc[5]), pack2(acc[6], acc[7]));
}

// ---------- squash: permuted part indexing; addPrev folds v += v_prev (bij-free) ----------
__global__ __launch_bounds__(256) void k_squash(const uint16_t* __restrict__ part,
                                                const float* __restrict__ bias,
                                                float* __restrict__ vout,
                                                float scale, int addBias, int addPrev) {
  const int lane = threadIdx.x & 63;
  const int row = blockIdx.x * 4 + (threadIdx.x >> 6);  // b=row>>6, o=row&63
  const int b = row >> 6, o = row & 63;
  const int d = lane & 31;
  const uint16_t* p = part + (size_t)b * (32 * OD_) +
                      (size_t)(d >> 3) * 512 + (size_t)o * 8 + (d & 7);
  float s = 0.f;
  const int c0 = (lane >> 5) * 16;   // half-waves split the 32 chunks
  for (int c = c0; c < c0 + 16; ++c)
    s += __uint_as_float(((uint32_t)p[(size_t)c * OD_]) << 16);
  s += __shfl_xor(s, 32);
  s *= scale;
  if (addBias) s += bias[o * 32 + d];
  float dot = s * s;
  #pragma unroll
  for (int off = 1; off <= 16; off <<= 1) dot += __shfl_xor(dot, off);
  float sc = dot / (1.f + dot) / sqrtf(dot + 1e-8f);
  if (lane < 32) {
    float val = s * sc;
    if (addPrev) val += vout[(size_t)row * 32 + d];
    vout[(size_t)row * 32 + d] = val;
  }
}

// ---------- route (iters 1,2): UNCHANGED from R12 (295.6-us best) ----------
// Next round finally reads this kernel's counters (VALUBusy / occupancy /
// VGPR / bank-conflict / hbm) and branches on the decision table.
__global__ __launch_bounds__(256) void k_route(const uint4* __restrict__ uhat,
                                               const float* __restrict__ vprev,
                                               uint4* __restrict__ part) {
  const int b = blockIdx.x >> 5, chunk = blockIdx.x & 31;
  const int t = threadIdx.x;
  const int w = t >> 6, lane = t & 63;   // lane = o
  __shared__ float red[4][64][32];       // 32 KB, swizzled [w][o][(d+o)&31]
  uint32_t vp[16];
  {
    const float4* vpt = (const float4*)(vprev + ((size_t)b * 64 + lane) * 32);
    #pragma unroll
    for (int q = 0; q < 8; ++q) {
      float4 f = vpt[q];
      vp[2 * q]     = pack2(f.x, f.y);
      vp[2 * q + 1] = pack2(f.z, f.w);
    }
  }
  float s_acc[32];
  #pragma unroll
  for (int d = 0; d < 32; ++d) s_acc[d] = 0.f;
  const int i0 = chunk * 32 + w * 8;
  const uint4* ub = uhat + ((size_t)b * I_ + i0) * 256 + lane;  // dense
  for (int r = 0; r < 8; ++r) {
    const uint4* uc = ub + (size_t)r * 256;
    uint4 c0 = uc[0], c1 = uc[64], c2 = uc[128], c3 = uc[192];
    float a = 0.f;
    {
      float u8[8];
      unpack8(c0, u8);
      #pragma unroll
      for (int p = 0; p < 4; ++p) {
        uint32_t vv = vp[p];
        a = fmaf(u8[2 * p], bflo(vv), a);
        a = fmaf(u8[2 * p + 1], bfhi(vv), a);
      }
      unpack8(c1, u8);
      #pragma unroll
      for (int p = 0; p < 4; ++p) {
        uint32_t vv = vp[4 + p];
        a = fmaf(u8[2 * p], bflo(vv), a);
        a = fmaf(u8[2 * p + 1], bfhi(vv), a);
      }
      unpack8(c2, u8);
      #pragma unroll
      for (int p = 0; p < 4; ++p) {
        uint32_t vv = vp[8 + p];
        a = fmaf(u8[2 * p], bflo(vv), a);
        a = fmaf(u8[2 * p + 1], bfhi(vv), a);
      }
      unpack8(c3, u8);
      #pragma unroll
      for (int p = 0; p < 4; ++p) {
        uint32_t vv = vp[12 + p];
        a = fmaf(u8[2 * p], bflo(vv), a);
        a = fmaf(u8[2 * p + 1], bfhi(vv), a);
      }
    }
    // wave softmax over the 64 o's
    float m = a;
    #pragma unroll
    for (int off = 1; off <= 32; off <<= 1) m = fmaxf(m, __shfl_xor(m, off));
    float e = __expf(a - m);
    float sm = e;
    #pragma unroll
    for (int off = 1; off <= 32; off <<= 1) sm += __shfl_xor(sm, off);
    const float c = e / sm;
    {
      float u8[8];
      unpack8(c0, u8);
      #pragma unroll
      for (int j = 0; j < 8; ++j) s_acc[j] = fmaf(c, u8[j], s_acc[j]);
      unpack8(c1, u8);
      #pragma unroll
      for (int j = 0; j < 8; ++j) s_acc[8 + j] = fmaf(c, u8[j], s_acc[8 + j]);
      unpack8(c2, u8);
      #pragma unroll
      for (int j = 0; j < 8; ++j) s_acc[16 + j] = fmaf(c, u8[j], s_acc[16 + j]);
      unpack8(c3, u8);
      #pragma unroll
      for (int j = 0; j < 8; ++j) s_acc[24 + j] = fmaf(c, u8[j], s_acc[24 + j]);
    }
  }
  // combine 4 waves' [o][d] partials (swizzle: 2 lanes/bank = free)
  #pragma unroll
  for (int d = 0; d < 32; ++d) red[w][lane][(d + lane) & 31] = s_acc[d];
  __syncthreads();
  {
    const int o = t & 63, k = t >> 6;    // thread stores uint4 at dense index t
    float sum[8];
    #pragma unroll
    for (int j = 0; j < 8; ++j) {
      const int sw = (k * 8 + j + o) & 31;
      sum[j] = red[0][o][sw] + red[1][o][sw] + red[2][o][sw] + red[3][o][sw];
    }
    part[((size_t)b * 32 + chunk) * 256 + t] =
        make_uint4(pack2(sum[0], sum[1]), pack2(sum[2], sum[3]),
                   pack2(sum[4], sum[5]), pack2(sum[6], sum[7]));
  }
}

extern "C" void kernel_launch(void* const* d_in, const int* in_sizes, int n_in,
                              void* d_out, int out_size, void* d_ws, size_t ws_size,
                              hipStream_t stream) {
  const float* x    = (const float*)d_in[0];  // [32,1024,16]
  const float* W    = (const float*)d_in[1];  // [1,1024,64,32,16]
  const float* bias = (const float*)d_in[2];  // [1,1,64,32]
  float* out = (float*)d_out;                 // [32,64,32]

  char* ws = (char*)d_ws;
  // Workspace layout (140.25 MiB — unchanged):
  //   [0,128M)      uhat  bf16 u_hat[b][i][k][o][j]  (permuted)
  //   [136,140M)    part  bf16 partials [b,32,·] (permuted rows)
  //   [140M,+256K)  vbuf  fp32 v[b,od]  (v0, then v0+v1 in place)
  uint16_t* uhat1 = (uint16_t*)ws;
  uint4*    uhat4 = (uint4*)ws;
  uint4* part = (uint4*)(ws + 134217728ull + 8388608ull);
  uint16_t* part16 = (uint16_t*)part;
  float* vbuf = (float*)(ws + 134217728ull + 8388608ull + 4194304ull);

  // einsum split into two od-half dispatches (each ~45 us < route ~80 us
  // -> route finally surfaces in the top-5 profile with full counters)
  k_einsum<<<dim3(I_ * 2), dim3(256), 0, stream>>>(x, W, uhat1, 0);
  k_einsum<<<dim3(I_ * 2), dim3(256), 0, stream>>>(x, W, uhat1, 2);
  // iter 0: uniform c = 1/64; v = v0
  k_sum0  <<<dim3(1024), dim3(256), 0, stream>>>(uhat4, part);
  k_squash<<<dim3(512),  dim3(256), 0, stream>>>(part16, bias, vbuf, 1.f / 64.f, 0, 0);
  // iter 1: c1 = softmax(u.v0); then v = v0+v1 (bij-free algebra)
  k_route <<<dim3(1024), dim3(256), 0, stream>>>(uhat4, vbuf, part);
  k_squash<<<dim3(512),  dim3(256), 0, stream>>>(part16, bias, vbuf, 1.f, 0, 1);
  // iter 2 (last): c2 = softmax(u.(v0+v1)); + bias -> output
  k_route <<<dim3(1024), dim3(256), 0, stream>>>(uhat4, vbuf, part);
  k_squash<<<dim3(512),  dim3(256), 0, stream>>>(part16, bias, out, 1.f, 1, 0);
}